// Round 2
// baseline (4095.538 us; speedup 1.0000x reference)
//
#include <hip/hip_runtime.h>

using u16 = unsigned short;
using u32 = unsigned int;

__device__ __forceinline__ u16 f2b(float f){
  u32 u = __builtin_bit_cast(u32, f);
  u += 0x7FFFu + ((u >> 16) & 1u);
  return (u16)(u >> 16);
}
__device__ __forceinline__ float b2f(u16 b){
  u32 u = ((u32)b) << 16;
  return __builtin_bit_cast(float, u);
}

// ---------------- sort by target (counting sort) ----------------

__global__ __launch_bounds__(256) void hist_k(const int* __restrict__ col, int* __restrict__ counts, int E){
  int e = blockIdx.x*256 + threadIdx.x;
  if (e < E) atomicAdd(&counts[col[e]], 1);
}

__global__ __launch_bounds__(1024) void scan1_k(const int* __restrict__ counts, int* __restrict__ start,
                                                int* __restrict__ bsum, int N){
  __shared__ int s[1024];
  int tid = threadIdx.x;
  int i = blockIdx.x*1024 + tid;
  int v = (i < N) ? counts[i] : 0;
  s[tid] = v; __syncthreads();
  for (int off = 1; off < 1024; off <<= 1){
    int t = (tid >= off) ? s[tid-off] : 0;
    __syncthreads();
    s[tid] += t;
    __syncthreads();
  }
  if (i < N) start[i] = s[tid] - v;     // block-local exclusive
  if (tid == 1023) bsum[blockIdx.x] = s[1023];
}

__global__ __launch_bounds__(1024) void scan2_k(int* __restrict__ bsum, int nb, int* __restrict__ start,
                                                int N, int E){
  __shared__ int s[1024];
  int tid = threadIdx.x;
  int v = (tid < nb) ? bsum[tid] : 0;
  s[tid] = v; __syncthreads();
  for (int off = 1; off < 1024; off <<= 1){
    int t = (tid >= off) ? s[tid-off] : 0;
    __syncthreads();
    s[tid] += t;
    __syncthreads();
  }
  if (tid < nb) bsum[tid] = s[tid] - v; // exclusive block offsets
  if (tid == 0) start[N] = E;
}

__global__ __launch_bounds__(1024) void scan3_k(int* __restrict__ start, const int* __restrict__ bsum,
                                                int* __restrict__ cursor, int N){
  int i = blockIdx.x*1024 + threadIdx.x;
  if (i < N){
    int v = start[i] + bsum[blockIdx.x];
    start[i] = v;
    cursor[i] = v;
  }
}

__global__ __launch_bounds__(256) void scat_k(const int* __restrict__ row, const int* __restrict__ col,
                                              int* __restrict__ cursor, int* __restrict__ perm,
                                              int* __restrict__ srcs, int* __restrict__ tgts, int E){
  int e = blockIdx.x*256 + threadIdx.x;
  if (e < E){
    int c = col[e];
    int p = atomicAdd(&cursor[c], 1);
    perm[p] = e;
    srcs[p] = row[e];
    tgts[p] = c;
  }
}

// ---------------- edge MLP helper (per-thread, weights in LDS, float4 broadcast reads) ----------

__device__ __forceinline__ void edge_mlp(const float a[8], const float* w1s, const float* w2s,
                                         u16* stage_row){
  float t1[64];
  #pragma unroll
  for (int h = 0; h < 64; h++){
    const float4* wv = (const float4*)&w1s[h*8];
    float4 b0 = wv[0], b1 = wv[1];
    float acc = a[0]*b0.x + a[1]*b0.y + a[2]*b0.z + a[3]*b0.w
              + a[4]*b1.x + a[5]*b1.y + a[6]*b1.z + a[7]*b1.w;
    t1[h] = fmaxf(acc, 0.f);
  }
  #pragma unroll 2
  for (int o = 0; o < 64; o++){
    const float4* wv = (const float4*)&w2s[o*64];
    float acc = 0.f;
    #pragma unroll
    for (int kq = 0; kq < 16; kq++){
      float4 w4 = wv[kq];
      acc += t1[4*kq]*w4.x + t1[4*kq+1]*w4.y + t1[4*kq+2]*w4.z + t1[4*kq+3]*w4.w;
    }
    stage_row[o] = f2b(fmaxf(acc, 0.f));
  }
}

// ---------------- PATH A: ew = relu(relu(ea@W1^T)@W2^T) -> bf16 global, sorted order ----------

__global__ __launch_bounds__(256) void ew_k(const float* __restrict__ ea, const float* __restrict__ W1,
                                            const float* __restrict__ W2, const int* __restrict__ perm,
                                            u16* __restrict__ ew, int E){
  __shared__ float w1s[64*8];
  __shared__ float w2s[64*64];
  __shared__ u16 stage[256*66];
  int tid = threadIdx.x;
  for (int i = tid; i < 512;  i += 256) w1s[i] = W1[i];
  for (int i = tid; i < 4096; i += 256) w2s[i] = W2[i];

  int j0 = blockIdx.x*256;
  int j  = j0 + tid;
  bool valid = j < E;
  int e = valid ? perm[j] : 0;
  const float4* eap = (const float4*)(ea + (size_t)e*8);
  float4 a0 = eap[0], a1 = eap[1];
  float a[8] = {a0.x,a0.y,a0.z,a0.w,a1.x,a1.y,a1.z,a1.w};
  __syncthreads();

  edge_mlp(a, w1s, w2s, &stage[tid*66]);
  __syncthreads();

  const u32* stg = (const u32*)stage;
  u32* outw = (u32*)ew;
  for (int w = tid; w < 256*32; w += 256){
    int el = w >> 5, oo = w & 31;
    int jj = j0 + el;
    if (jj < E) outw[(size_t)jj*32 + oo] = stg[el*33 + oo];
  }
}

__global__ __launch_bounds__(256) void deg_k(const u16* __restrict__ ew, const int* __restrict__ start,
                                             float* __restrict__ dinv, int N){
  int wv = threadIdx.x >> 6, lane = threadIdx.x & 63;
  int n = blockIdx.x*4 + wv;
  if (n >= N) return;
  int s = start[n], e = start[n+1];
  float d = 1.f;
  for (int j = s; j < e; j++) d += b2f(ew[(size_t)j*64 + lane]);
  dinv[(size_t)n*64 + lane] = rsqrtf(d);
}

__global__ __launch_bounds__(256) void layer_k(const float* __restrict__ xlin, const float* __restrict__ xws_in,
                                               const u16* __restrict__ ew, const int* __restrict__ start,
                                               const int* __restrict__ srcs, const float* __restrict__ dinv,
                                               const float* __restrict__ Wl, const float* __restrict__ bconv,
                                               const float* __restrict__ wconv_next,
                                               float* __restrict__ outb, int N, int last){
  __shared__ float wt[128*64];
  __shared__ float gs[4][64];
  __shared__ float xls[4][64];
  int tid = threadIdx.x;
  for (int i = tid; i < 8192; i += 256){ int o = i >> 7, c = i & 127; wt[c*64+o] = Wl[i]; }
  int wv = tid >> 6, lane = tid & 63;
  int n = blockIdx.x*4 + wv;
  float xl = 0.f, dv = 0.f;
  if (n < N){
    xl = xlin[(size_t)n*64 + lane];
    dv = dinv[(size_t)n*64 + lane];
    int s = start[n], epos = start[n+1];
    float acc = xws_in[(size_t)n*64 + lane];
    for (int j = s; j < epos; j++){
      int src = srcs[j];
      acc += b2f(ew[(size_t)j*64 + lane]) * xws_in[(size_t)src*64 + lane];
    }
    float g = dv*acc + bconv[lane];
    gs[wv][lane] = g;
    xls[wv][lane] = xl;
  }
  __syncthreads();
  if (n >= N) return;
  float h = xl;
  #pragma unroll 8
  for (int k = 0; k < 64; k++) h += xls[wv][k]*wt[k*64+lane];
  #pragma unroll 8
  for (int k = 0; k < 64; k++) h += gs[wv][k]*wt[(64+k)*64+lane];
  float r = fmaxf(h, 0.f);
  outb[(size_t)n*64 + lane] = last ? r : r * wconv_next[lane] * dv;
}

// ---------------- PATH C: edge-parallel recompute + segmented atomic aggregation ----------

template<int MODE>  // 0 = degree (xws==1), 1 = layer (gather xws)
__global__ __launch_bounds__(256) void edge_agg_k(const float* __restrict__ ea, const float* __restrict__ W1,
                                                  const float* __restrict__ W2, const int* __restrict__ perm,
                                                  const int* __restrict__ srcs, const int* __restrict__ tgts,
                                                  const float* __restrict__ xws, float* __restrict__ U, int E){
  __shared__ float w1s[512];
  __shared__ float w2s[4096];
  __shared__ u16 stage[256*66];
  __shared__ int sl[256], tl[256];
  int tid = threadIdx.x;
  for (int i = tid; i < 512;  i += 256) w1s[i] = W1[i];
  for (int i = tid; i < 4096; i += 256) w2s[i] = W2[i];

  int j0 = blockIdx.x*256;
  int j  = j0 + tid;
  bool valid = j < E;
  int e = valid ? perm[j] : 0;
  sl[tid] = valid ? srcs[j] : 0;
  tl[tid] = valid ? tgts[j] : 0;
  const float4* eap = (const float4*)(ea + (size_t)e*8);
  float4 a0 = eap[0], a1 = eap[1];
  float a[8] = {a0.x,a0.y,a0.z,a0.w,a1.x,a1.y,a1.z,a1.w};
  __syncthreads();

  edge_mlp(a, w1s, w2s, &stage[tid*66]);
  __syncthreads();

  // wave w scans 64 sorted edges; lane = channel; flush on target change
  int w = tid >> 6, lane = tid & 63;
  int base = w*64;
  int lim = E - (j0 + base); if (lim > 64) lim = 64;
  if (lim > 0){
    float acc = 0.f;
    int cur = tl[base];
    for (int q = 0; q < lim; q++){
      int t = tl[base+q];                 // wave-uniform
      if (t != cur){
        atomicAdd(&U[(size_t)cur*64 + lane], acc);
        acc = 0.f; cur = t;
      }
      float wv = b2f(stage[(base+q)*66 + lane]);
      float xv = MODE ? xws[(size_t)sl[base+q]*64 + lane] : 1.f;
      acc += wv*xv;
    }
    atomicAdd(&U[(size_t)cur*64 + lane], acc);
  }
}

__global__ __launch_bounds__(256) void degfin_k(float* __restrict__ U, float* __restrict__ dinv, int NH){
  int i = blockIdx.x*256 + threadIdx.x;
  if (i < NH){
    dinv[i] = rsqrtf(1.f + U[i]);
    U[i] = 0.f;
  }
}

// epilogue: self-loop + dinv + bias, then mixing linear + residual; re-zero U
__global__ __launch_bounds__(256) void epiC_k(const float* __restrict__ xlin, const float* __restrict__ dinv,
                                              float* __restrict__ U, float* __restrict__ V,
                                              const float* __restrict__ Wl, const float* __restrict__ bconv,
                                              const float* __restrict__ wconv_next, int N, int last){
  __shared__ float wt[128*64];
  __shared__ float gs[4][64];
  __shared__ float xls[4][64];
  int tid = threadIdx.x;
  for (int i = tid; i < 8192; i += 256){ int o = i >> 7, c = i & 127; wt[c*64+o] = Wl[i]; }
  int wv = tid >> 6, lane = tid & 63;
  int n = blockIdx.x*4 + wv;
  float xl = 0.f, dv = 0.f;
  if (n < N){
    xl = xlin[(size_t)n*64 + lane];
    dv = dinv[(size_t)n*64 + lane];
    float self = V[(size_t)n*64 + lane];           // dinv-folded self-loop term
    float g = dv*(self + U[(size_t)n*64 + lane]) + bconv[lane];
    gs[wv][lane] = g;
    xls[wv][lane] = xl;
  }
  __syncthreads();
  if (n >= N) return;
  float h = xl;
  #pragma unroll 8
  for (int k = 0; k < 64; k++) h += xls[wv][k]*wt[k*64+lane];
  #pragma unroll 8
  for (int k = 0; k < 64; k++) h += gs[wv][k]*wt[(64+k)*64+lane];
  float r = fmaxf(h, 0.f);
  V[(size_t)n*64 + lane] = last ? r : r * wconv_next[lane] * dv;
  U[(size_t)n*64 + lane] = 0.f;                    // accumulator ready for next pass
}

// ---------------- shared: x_ = x@Wi^T + bi ; xws0 = dinv*relu(x_)*w_conv[0] ----------

__global__ __launch_bounds__(256) void xlin_k(const float* __restrict__ x, const float* __restrict__ Wi,
                                              const float* __restrict__ bi, const float* __restrict__ wconv0,
                                              const float* __restrict__ dinv,
                                              float* __restrict__ xlin, float* __restrict__ xws, int N){
  __shared__ float wt[128*64];
  __shared__ float xs[4][128];
  int tid = threadIdx.x;
  for (int i = tid; i < 8192; i += 256){ int o = i >> 7, k = i & 127; wt[k*64+o] = Wi[i]; }
  int wv = tid >> 6, lane = tid & 63;
  int n = blockIdx.x*4 + wv;
  if (n < N){
    xs[wv][lane]      = x[(size_t)n*128 + lane];
    xs[wv][lane+64]   = x[(size_t)n*128 + 64 + lane];
  }
  __syncthreads();
  if (n >= N) return;
  float acc = bi[lane];
  #pragma unroll 8
  for (int k = 0; k < 128; k++) acc += xs[wv][k]*wt[k*64+lane];
  xlin[(size_t)n*64 + lane] = acc;
  float v = fmaxf(acc, 0.f) * wconv0[lane] * dinv[(size_t)n*64 + lane];
  xws[(size_t)n*64 + lane] = v;
}

// ---------------- out = concat(x_, relu(h3)) @ Wo^T ----------------

__global__ __launch_bounds__(256) void out_k(const float* __restrict__ xlin, const float* __restrict__ hr,
                                             const float* __restrict__ Wo, float* __restrict__ out, int N){
  int wv = threadIdx.x >> 6, lane = threadIdx.x & 63;
  int n = blockIdx.x*4 + wv;
  if (n >= N) return;
  float v = xlin[(size_t)n*64 + lane]*Wo[lane] + hr[(size_t)n*64 + lane]*Wo[64 + lane];
  #pragma unroll
  for (int off = 32; off > 0; off >>= 1) v += __shfl_down(v, off, 64);
  if (lane == 0) out[n] = v;
}

extern "C" void kernel_launch(void* const* d_in, const int* in_sizes, int n_in,
                              void* d_out, int out_size, void* d_ws, size_t ws_size,
                              hipStream_t stream){
  const float* x     = (const float*)d_in[0];
  const int*   ei    = (const int*)  d_in[1];
  const float* ea    = (const float*)d_in[2];
  const float* W1    = (const float*)d_in[3];
  const float* W2    = (const float*)d_in[4];
  const float* Wi    = (const float*)d_in[5];
  const float* bi    = (const float*)d_in[6];
  const float* wconv = (const float*)d_in[7];
  const float* bconv = (const float*)d_in[8];
  const float* Wl    = (const float*)d_in[9];
  const float* Wo    = (const float*)d_in[10];
  float* out = (float*)d_out;

  int N = in_sizes[0] / 128;
  int E = in_sizes[2] / 8;
  const int* row = ei;
  const int* col = ei + E;

  char* p = (char*)d_ws;
  auto alloc = [&](size_t nbytes){ char* r = p; p += (nbytes + 255) & ~(size_t)255; return r; };
  auto asz = [](size_t nbytes){ return (nbytes + 255) & ~(size_t)255; };

  // common CSR
  int*   counts = (int*)  alloc((size_t)N*4);
  int*   start  = (int*)  alloc((size_t)(N+1)*4);
  int*   cursor = (int*)  alloc((size_t)N*4);
  int*   bsum   = (int*)  alloc(4096);
  int*   perm   = (int*)  alloc((size_t)E*4);
  int*   srcs   = (int*)  alloc((size_t)E*4);
  int*   tgts   = (int*)  alloc((size_t)E*4);

  size_t common = asz((size_t)N*4)*2 + asz((size_t)(N+1)*4) + asz(4096) + asz((size_t)E*4)*3;
  size_t nodeb  = asz((size_t)N*256);
  size_t needA  = common + asz((size_t)E*128) + 4*nodeb;
  bool useA = (ws_size >= needA);

  int gE  = (E + 255) / 256;
  int nb1 = (N + 1023) / 1024;
  int gN4 = (N + 3) / 4;

  hipMemsetAsync(counts, 0, (size_t)N*4, stream);
  hist_k <<<gE, 256, 0, stream>>>(col, counts, E);
  scan1_k<<<nb1, 1024, 0, stream>>>(counts, start, bsum, N);
  scan2_k<<<1, 1024, 0, stream>>>(bsum, nb1, start, N, E);
  scan3_k<<<nb1, 1024, 0, stream>>>(start, bsum, cursor, N);
  scat_k <<<gE, 256, 0, stream>>>(row, col, cursor, perm, srcs, tgts, E);

  if (useA){
    u16*   ew   = (u16*)  alloc((size_t)E*128);
    float* dinv = (float*)alloc(nodeb);
    float* xlin = (float*)alloc(nodeb);
    float* bufA = (float*)alloc(nodeb);
    float* bufB = (float*)alloc(nodeb);

    ew_k   <<<gE, 256, 0, stream>>>(ea, W1, W2, perm, ew, E);
    deg_k  <<<gN4, 256, 0, stream>>>(ew, start, dinv, N);
    xlin_k <<<gN4, 256, 0, stream>>>(x, Wi, bi, wconv, dinv, xlin, bufA, N);
    layer_k<<<gN4, 256, 0, stream>>>(xlin, bufA, ew, start, srcs, dinv, Wl + 0*8192, bconv +   0, wconv +  64, bufB, N, 0);
    layer_k<<<gN4, 256, 0, stream>>>(xlin, bufB, ew, start, srcs, dinv, Wl + 1*8192, bconv +  64, wconv + 128, bufA, N, 0);
    layer_k<<<gN4, 256, 0, stream>>>(xlin, bufA, ew, start, srcs, dinv, Wl + 2*8192, bconv + 128, wconv      , bufB, N, 1);
    out_k  <<<gN4, 256, 0, stream>>>(xlin, bufB, Wo, out, N);
  } else {
    float* dinv = (float*)alloc(nodeb);
    float* xlin = (float*)alloc(nodeb);
    float* U    = (float*)alloc(nodeb);   // atomic accumulator
    float* V    = (float*)alloc(nodeb);   // xws ping buffer

    hipMemsetAsync(U, 0, (size_t)N*256, stream);
    int gNH = (N*64 + 255) / 256;

    edge_agg_k<0><<<gE, 256, 0, stream>>>(ea, W1, W2, perm, srcs, tgts, V, U, E);   // degree
    degfin_k  <<<gNH, 256, 0, stream>>>(U, dinv, N*64);                             // dinv, U=0
    xlin_k    <<<gN4, 256, 0, stream>>>(x, Wi, bi, wconv, dinv, xlin, V, N);        // xlin, V=xws0
    edge_agg_k<1><<<gE, 256, 0, stream>>>(ea, W1, W2, perm, srcs, tgts, V, U, E);
    epiC_k    <<<gN4, 256, 0, stream>>>(xlin, dinv, U, V, Wl + 0*8192, bconv +   0, wconv +  64, N, 0);
    edge_agg_k<1><<<gE, 256, 0, stream>>>(ea, W1, W2, perm, srcs, tgts, V, U, E);
    epiC_k    <<<gN4, 256, 0, stream>>>(xlin, dinv, U, V, Wl + 1*8192, bconv +  64, wconv + 128, N, 0);
    edge_agg_k<1><<<gE, 256, 0, stream>>>(ea, W1, W2, perm, srcs, tgts, V, U, E);
    epiC_k    <<<gN4, 256, 0, stream>>>(xlin, dinv, U, V, Wl + 2*8192, bconv + 128, wconv      , N, 1);
    out_k     <<<gN4, 256, 0, stream>>>(xlin, V, Wo, out, N);
  }
}

// Round 3
// 1966.638 us; speedup vs baseline: 2.0825x; 2.0825x over previous
//
#include <hip/hip_runtime.h>

using u16 = unsigned short;
using u32 = unsigned int;

typedef __bf16 v8bf __attribute__((ext_vector_type(8)));
typedef float  v4f  __attribute__((ext_vector_type(4)));

#define ST 72   // u16 stride for 64-wide bf16 LDS rows (144 B: 16B-aligned, balanced banks)

__device__ __forceinline__ u16 f2b(float f){
  u32 u = __builtin_bit_cast(u32, f);
  u += 0x7FFFu + ((u >> 16) & 1u);
  return (u16)(u >> 16);
}
__device__ __forceinline__ float b2f(u16 b){
  u32 u = ((u32)b) << 16;
  return __builtin_bit_cast(float, u);
}

// ---------------- counting sort by target ----------------

__global__ __launch_bounds__(256) void hist_k(const int* __restrict__ col, int* __restrict__ counts, int E){
  int e = blockIdx.x*256 + threadIdx.x;
  if (e < E) atomicAdd(&counts[col[e]], 1);
}

__global__ __launch_bounds__(1024) void scan1_k(const int* __restrict__ counts, int* __restrict__ start,
                                                int* __restrict__ bsum, int N){
  __shared__ int s[1024];
  int tid = threadIdx.x;
  int i = blockIdx.x*1024 + tid;
  int v = (i < N) ? counts[i] : 0;
  s[tid] = v; __syncthreads();
  for (int off = 1; off < 1024; off <<= 1){
    int t = (tid >= off) ? s[tid-off] : 0;
    __syncthreads();
    s[tid] += t;
    __syncthreads();
  }
  if (i < N) start[i] = s[tid] - v;
  if (tid == 1023) bsum[blockIdx.x] = s[1023];
}

__global__ __launch_bounds__(1024) void scan2_k(int* __restrict__ bsum, int nb, int* __restrict__ start,
                                                int N, int E){
  __shared__ int s[1024];
  int tid = threadIdx.x;
  int v = (tid < nb) ? bsum[tid] : 0;
  s[tid] = v; __syncthreads();
  for (int off = 1; off < 1024; off <<= 1){
    int t = (tid >= off) ? s[tid-off] : 0;
    __syncthreads();
    s[tid] += t;
    __syncthreads();
  }
  if (tid < nb) bsum[tid] = s[tid] - v;
  if (tid == 0) start[N] = E;
}

__global__ __launch_bounds__(1024) void scan3_k(int* __restrict__ start, const int* __restrict__ bsum,
                                                int* __restrict__ cursor, int N){
  int i = blockIdx.x*1024 + threadIdx.x;
  if (i < N){
    int v = start[i] + bsum[blockIdx.x];
    start[i] = v;
    cursor[i] = v;
  }
}

__global__ __launch_bounds__(256) void scat_k(const int* __restrict__ col, int* __restrict__ cursor,
                                              int* __restrict__ perm, int E){
  int e = blockIdx.x*256 + threadIdx.x;
  if (e < E){
    int p = atomicAdd(&cursor[col[e]], 1);
    perm[p] = e;
  }
}

__global__ __launch_bounds__(256) void fill_k(const int* __restrict__ row, const int* __restrict__ perm,
                                              int* __restrict__ srcs, int E){
  int j = blockIdx.x*256 + threadIdx.x;
  if (j < E) srcs[j] = row[perm[j]];
}

__global__ __launch_bounds__(256) void tgt_k(const int* __restrict__ start, int* __restrict__ tgts, int N){
  int w = threadIdx.x >> 6, lane = threadIdx.x & 63;
  int n = blockIdx.x*4 + w;
  if (n >= N) return;
  int e = start[n+1];
  for (int j = start[n] + lane; j < e; j += 64) tgts[j] = n;
}

// ---------------- fused edge-MLP (MFMA) + segmented aggregation ----------------
// block = 256 threads / 4 waves, 256 sorted edges. All stage LDS is wave-local.

template<int MODE>   // 0: degree (xv=1, no srcs/V)   1: layer (gather V bf16)
__global__ __launch_bounds__(256) void agg_k(const float* __restrict__ ea, const float* __restrict__ W1,
                                             const float* __restrict__ W2, const int* __restrict__ perm,
                                             const int* __restrict__ srcs, const int* __restrict__ tgts,
                                             const u16* __restrict__ V, float* __restrict__ U, int E){
  __shared__ __align__(16) u16 stage[256*ST];   // t1 (bf16), then ew (bf16)
  __shared__ __align__(16) u16 w2s[64*ST];      // W2 bf16, row-major
  __shared__ float w1s[512];
  __shared__ int sl[256], tl[256];
  int tid = threadIdx.x;
  for (int i = tid; i < 512;  i += 256) w1s[i] = W1[i];
  for (int i = tid; i < 4096; i += 256) w2s[(i>>6)*ST + (i&63)] = f2b(W2[i]);

  int j0 = blockIdx.x*256, j = j0 + tid;
  bool valid = j < E;
  int e = valid ? perm[j] : 0;
  if (MODE) sl[tid] = valid ? srcs[j] : 0;
  tl[tid] = valid ? tgts[j] : 0;
  const float4* eap = (const float4*)(ea + (size_t)e*8);
  float4 a0 = eap[0], a1 = eap[1];
  float a[8] = {a0.x,a0.y,a0.z,a0.w,a1.x,a1.y,a1.z,a1.w};
  __syncthreads();   // w1s/w2s ready (stage/sl/tl are wave-local)

  // layer 1: t1 = relu(a @ W1^T) -> stage[tid][*] bf16
  #pragma unroll
  for (int h0 = 0; h0 < 64; h0 += 4){
    ushort4 pk;
    u16* pp = (u16*)&pk;
    #pragma unroll
    for (int hh = 0; hh < 4; hh++){
      const float4* wv = (const float4*)&w1s[(h0+hh)*8];
      float4 b0 = wv[0], b1 = wv[1];
      float acc = a[0]*b0.x + a[1]*b0.y + a[2]*b0.z + a[3]*b0.w
                + a[4]*b1.x + a[5]*b1.y + a[6]*b1.z + a[7]*b1.w;
      pp[hh] = f2b(fmaxf(acc, 0.f));
    }
    *(ushort4*)&stage[tid*ST + h0] = pk;
  }

  // layer 2 via MFMA: wave w computes its 64 edges x 64 channels
  int w = tid >> 6, lane = tid & 63;
  int m16 = lane & 15, quad = lane >> 4;

  v8bf bfr[2][4];
  #pragma unroll
  for (int ks = 0; ks < 2; ks++)
    #pragma unroll
    for (int ni = 0; ni < 4; ni++)
      bfr[ks][ni] = *(const v8bf*)&w2s[(ni*16 + m16)*ST + ks*32 + quad*8];

  v4f acc[4][4];
  #pragma unroll
  for (int mi = 0; mi < 4; mi++)
    #pragma unroll
    for (int ni = 0; ni < 4; ni++)
      acc[mi][ni] = (v4f){0.f,0.f,0.f,0.f};

  #pragma unroll
  for (int mi = 0; mi < 4; mi++){
    #pragma unroll
    for (int ks = 0; ks < 2; ks++){
      v8bf af = *(const v8bf*)&stage[(w*64 + mi*16 + m16)*ST + ks*32 + quad*8];
      #pragma unroll
      for (int ni = 0; ni < 4; ni++)
        acc[mi][ni] = __builtin_amdgcn_mfma_f32_16x16x32_bf16(af, bfr[ks][ni], acc[mi][ni], 0, 0, 0);
    }
  }

  // ew = relu(acc) -> stage (own wave's rows; in-order DS makes this safe)
  #pragma unroll
  for (int mi = 0; mi < 4; mi++)
    #pragma unroll
    for (int ni = 0; ni < 4; ni++)
      #pragma unroll
      for (int r = 0; r < 4; r++){
        int m = mi*16 + quad*4 + r;
        int n = ni*16 + m16;
        stage[(w*64 + m)*ST + n] = f2b(fmaxf(acc[mi][ni][r], 0.f));
      }

  // segmented scan over this wave's 64 sorted edges; lane = channel
  int base = w*64;
  int lim = E - (j0 + base); if (lim > 64) lim = 64;
  if (lim > 0){
    float s = 0.f;
    int cur = tl[base];
    for (int q0 = 0; q0 < lim; q0 += 8){
      int qm = lim - q0; if (qm > 8) qm = 8;
      float xv[8], wv[8];
      #pragma unroll
      for (int q = 0; q < 8; q++){
        if (q < qm){
          wv[q] = b2f(stage[(base+q0+q)*ST + lane]);
          xv[q] = MODE ? b2f(V[(size_t)sl[base+q0+q]*64 + lane]) : 1.f;
        }
      }
      #pragma unroll
      for (int q = 0; q < 8; q++){
        if (q < qm){
          int t = tl[base+q0+q];
          if (t != cur){ atomicAdd(&U[(size_t)cur*64 + lane], s); s = 0.f; cur = t; }
          s += wv[q]*xv[q];
        }
      }
    }
    atomicAdd(&U[(size_t)cur*64 + lane], s);
  }
}

__global__ __launch_bounds__(256) void degfin_k(float* __restrict__ U, float* __restrict__ dinv, int NH){
  int i = blockIdx.x*256 + threadIdx.x;
  if (i < NH){
    dinv[i] = rsqrtf(1.f + U[i]);
    U[i] = 0.f;
  }
}

// ---------------- x_ = x@Wi^T + bi ; V0 = bf16(dinv*relu(x_)*wconv0) — 16 nodes/block ----------

__global__ __launch_bounds__(256) void xlin_k(const float* __restrict__ x, const float* __restrict__ Wi,
                                              const float* __restrict__ bi, const float* __restrict__ wconv0,
                                              const float* __restrict__ dinv,
                                              float* __restrict__ xlin, u16* __restrict__ V, int N){
  __shared__ float wt[128*64];   // WiT[k][o]
  __shared__ float xs[16][128];
  int tid = threadIdx.x;
  for (int i = tid; i < 8192; i += 256){ int o = i >> 7, k = i & 127; wt[k*64+o] = Wi[i]; }
  int nb0 = blockIdx.x*16;
  for (int i = tid; i < 2048; i += 256){
    int nn = i >> 7, k = i & 127; int n = nb0 + nn;
    xs[nn][k] = (n < N) ? x[(size_t)n*128 + k] : 0.f;
  }
  __syncthreads();
  int w = tid >> 6, lane = tid & 63;
  for (int nn = w; nn < 16; nn += 4){
    int n = nb0 + nn; if (n >= N) continue;
    float acc = bi[lane];
    #pragma unroll 8
    for (int k = 0; k < 128; k++) acc += xs[nn][k]*wt[k*64+lane];
    xlin[(size_t)n*64 + lane] = acc;
    float v = fmaxf(acc, 0.f) * wconv0[lane] * dinv[(size_t)n*64 + lane];
    V[(size_t)n*64 + lane] = f2b(v);
  }
}

// ---------------- epilogue: conv-finish + mixing + residual (+ fused output) — 16 nodes/block ----

__global__ __launch_bounds__(256) void epi_k(const float* __restrict__ xlin, const float* __restrict__ dinv,
                                             float* __restrict__ U, u16* __restrict__ V,
                                             const float* __restrict__ Wl, const float* __restrict__ bconv,
                                             const float* __restrict__ wconv_next, const float* __restrict__ Wo,
                                             float* __restrict__ out, int N, int last){
  __shared__ float wt[128*64];   // WlT[c][o]
  __shared__ float gs[16][64];
  __shared__ float xls[16][64];
  int tid = threadIdx.x;
  for (int i = tid; i < 8192; i += 256){ int o = i >> 7, c = i & 127; wt[c*64+o] = Wl[i]; }
  int nb0 = blockIdx.x*16;
  for (int i = tid; i < 1024; i += 256){
    int nn = i >> 6, c = i & 63; int n = nb0 + nn;
    if (n < N){
      size_t idx = (size_t)n*64 + c;
      xls[nn][c] = xlin[idx];
      gs[nn][c]  = dinv[idx]*(b2f(V[idx]) + U[idx]) + bconv[c];
    }
  }
  __syncthreads();
  int w = tid >> 6, lane = tid & 63;
  for (int nn = w; nn < 16; nn += 4){
    int n = nb0 + nn; if (n >= N) continue;
    float h = xls[nn][lane];
    #pragma unroll 8
    for (int k = 0; k < 64; k++) h += xls[nn][k]*wt[k*64+lane];
    #pragma unroll 8
    for (int k = 0; k < 64; k++) h += gs[nn][k]*wt[(64+k)*64+lane];
    float r = fmaxf(h, 0.f);
    size_t idx = (size_t)n*64 + lane;
    if (!last){
      V[idx] = f2b(r * wconv_next[lane] * dinv[idx]);
      U[idx] = 0.f;
    } else {
      float v = xls[nn][lane]*Wo[lane] + r*Wo[64 + lane];
      #pragma unroll
      for (int off = 32; off > 0; off >>= 1) v += __shfl_down(v, off, 64);
      if (lane == 0) out[n] = v;
    }
  }
}

extern "C" void kernel_launch(void* const* d_in, const int* in_sizes, int n_in,
                              void* d_out, int out_size, void* d_ws, size_t ws_size,
                              hipStream_t stream){
  const float* x     = (const float*)d_in[0];
  const int*   ei    = (const int*)  d_in[1];
  const float* ea    = (const float*)d_in[2];
  const float* W1    = (const float*)d_in[3];
  const float* W2    = (const float*)d_in[4];
  const float* Wi    = (const float*)d_in[5];
  const float* bi    = (const float*)d_in[6];
  const float* wconv = (const float*)d_in[7];
  const float* bconv = (const float*)d_in[8];
  const float* Wl    = (const float*)d_in[9];
  const float* Wo    = (const float*)d_in[10];
  float* out = (float*)d_out;

  int N = in_sizes[0] / 128;
  int E = in_sizes[2] / 8;
  const int* row = ei;
  const int* col = ei + E;

  char* p = (char*)d_ws;
  auto alloc = [&](size_t nbytes){ char* r = p; p += (nbytes + 255) & ~(size_t)255; return r; };

  int*   counts = (int*)  alloc((size_t)N*4);
  int*   start  = (int*)  alloc((size_t)(N+1)*4);
  int*   cursor = (int*)  alloc((size_t)N*4);
  int*   bsum   = (int*)  alloc(4096);
  int*   perm   = (int*)  alloc((size_t)E*4);
  int*   srcs   = (int*)  alloc((size_t)E*4);
  int*   tgts   = (int*)  alloc((size_t)E*4);
  float* U      = (float*)alloc((size_t)N*256);
  float* dinv   = (float*)alloc((size_t)N*256);
  float* xlin   = (float*)alloc((size_t)N*256);
  u16*   V      = (u16*)  alloc((size_t)N*128);

  int gE   = (E + 255) / 256;
  int nb1  = (N + 1023) / 1024;
  int gN4  = (N + 3) / 4;
  int gN16 = (N + 15) / 16;
  int gNH  = (N*64 + 255) / 256;

  hipMemsetAsync(counts, 0, (size_t)N*4, stream);
  hipMemsetAsync(U, 0, (size_t)N*256, stream);

  hist_k <<<gE, 256, 0, stream>>>(col, counts, E);
  scan1_k<<<nb1, 1024, 0, stream>>>(counts, start, bsum, N);
  scan2_k<<<1, 1024, 0, stream>>>(bsum, nb1, start, N, E);
  scan3_k<<<nb1, 1024, 0, stream>>>(start, bsum, cursor, N);
  scat_k <<<gE, 256, 0, stream>>>(col, cursor, perm, E);
  fill_k <<<gE, 256, 0, stream>>>(row, perm, srcs, E);
  tgt_k  <<<gN4, 256, 0, stream>>>(start, tgts, N);

  agg_k<0><<<gE, 256, 0, stream>>>(ea, W1, W2, perm, srcs, tgts, V, U, E);   // degree
  degfin_k<<<gNH, 256, 0, stream>>>(U, dinv, N*64);
  xlin_k  <<<gN16, 256, 0, stream>>>(x, Wi, bi, wconv, dinv, xlin, V, N);

  agg_k<1><<<gE, 256, 0, stream>>>(ea, W1, W2, perm, srcs, tgts, V, U, E);
  epi_k   <<<gN16, 256, 0, stream>>>(xlin, dinv, U, V, Wl + 0*8192, bconv +   0, wconv +  64, Wo, out, N, 0);
  agg_k<1><<<gE, 256, 0, stream>>>(ea, W1, W2, perm, srcs, tgts, V, U, E);
  epi_k   <<<gN16, 256, 0, stream>>>(xlin, dinv, U, V, Wl + 1*8192, bconv +  64, wconv + 128, Wo, out, N, 0);
  agg_k<1><<<gE, 256, 0, stream>>>(ea, W1, W2, perm, srcs, tgts, V, U, E);
  epi_k   <<<gN16, 256, 0, stream>>>(xlin, dinv, U, V, Wl + 2*8192, bconv + 128, wconv      , Wo, out, N, 1);
}

// Round 4
// 1450.296 us; speedup vs baseline: 2.8239x; 1.3560x over previous
//
#include <hip/hip_runtime.h>

using u16 = unsigned short;
using u32 = unsigned int;

typedef __bf16 v8bf __attribute__((ext_vector_type(8)));
typedef float  v4f  __attribute__((ext_vector_type(4)));

#define ST  68    // u16 stride for 64-wide bf16 LDS rows (34 dwords: 2-way max on b128 frag reads)
#define EPB 128   // edges per block (256 threads, 4 waves, 32 edges/wave)

__device__ __forceinline__ u16 f2b(float f){
  u32 u = __builtin_bit_cast(u32, f);
  u += 0x7FFFu + ((u >> 16) & 1u);
  return (u16)(u >> 16);
}
__device__ __forceinline__ float b2f(u16 b){
  u32 u = ((u32)b) << 16;
  return __builtin_bit_cast(float, u);
}

union bfu { v8bf v; u16 s[8]; };

__device__ __forceinline__ v8bf zero8(){
  bfu u;
  #pragma unroll
  for (int i = 0; i < 8; i++) u.s[i] = 0;
  return u.v;
}
__device__ __forceinline__ v8bf pack8(float4 a, float4 b){
  bfu u;
  u.s[0]=f2b(a.x); u.s[1]=f2b(a.y); u.s[2]=f2b(a.z); u.s[3]=f2b(a.w);
  u.s[4]=f2b(b.x); u.s[5]=f2b(b.y); u.s[6]=f2b(b.z); u.s[7]=f2b(b.w);
  return u.v;
}

// ---------------- counting sort by target ----------------

__global__ __launch_bounds__(256) void hist_k(const int* __restrict__ col, int* __restrict__ counts, int E){
  int e = blockIdx.x*256 + threadIdx.x;
  if (e < E) atomicAdd(&counts[col[e]], 1);
}

__global__ __launch_bounds__(1024) void scan1_k(const int* __restrict__ counts, int* __restrict__ start,
                                                int* __restrict__ bsum, int N){
  __shared__ int s[1024];
  int tid = threadIdx.x;
  int i = blockIdx.x*1024 + tid;
  int v = (i < N) ? counts[i] : 0;
  s[tid] = v; __syncthreads();
  for (int off = 1; off < 1024; off <<= 1){
    int t = (tid >= off) ? s[tid-off] : 0;
    __syncthreads();
    s[tid] += t;
    __syncthreads();
  }
  if (i < N) start[i] = s[tid] - v;
  if (tid == 1023) bsum[blockIdx.x] = s[1023];
}

__global__ __launch_bounds__(1024) void scan2_k(int* __restrict__ bsum, int nb, int* __restrict__ start,
                                                int N, int E){
  __shared__ int s[1024];
  int tid = threadIdx.x;
  int v = (tid < nb) ? bsum[tid] : 0;
  s[tid] = v; __syncthreads();
  for (int off = 1; off < 1024; off <<= 1){
    int t = (tid >= off) ? s[tid-off] : 0;
    __syncthreads();
    s[tid] += t;
    __syncthreads();
  }
  if (tid < nb) bsum[tid] = s[tid] - v;
  if (tid == 0) start[N] = E;
}

__global__ __launch_bounds__(1024) void scan3_k(int* __restrict__ start, const int* __restrict__ bsum,
                                                int* __restrict__ cursor, int N){
  int i = blockIdx.x*1024 + threadIdx.x;
  if (i < N){
    int v = start[i] + bsum[blockIdx.x];
    start[i] = v;
    cursor[i] = v;
  }
}

__global__ __launch_bounds__(256) void scat_k(const int* __restrict__ col, int* __restrict__ cursor,
                                              int* __restrict__ perm, int E){
  int e = blockIdx.x*256 + threadIdx.x;
  if (e < E){
    int p = atomicAdd(&cursor[col[e]], 1);
    perm[p] = e;
  }
}

__global__ __launch_bounds__(256) void fill_k(const int* __restrict__ row, const int* __restrict__ perm,
                                              int* __restrict__ srcs, int E){
  int j = blockIdx.x*256 + threadIdx.x;
  if (j < E) srcs[j] = row[perm[j]];
}

__global__ __launch_bounds__(256) void tgt_k(const int* __restrict__ start, int* __restrict__ tgts, int N){
  int w = threadIdx.x >> 6, lane = threadIdx.x & 63;
  int n = blockIdx.x*4 + w;
  if (n >= N) return;
  int e = start[n+1];
  for (int j = start[n] + lane; j < e; j += 64) tgts[j] = n;
}

// ---------------- fused edge-MLP (both layers MFMA) + segmented aggregation ----------------
// 256 threads / 4 waves, 128 sorted edges; each wave owns 32 edges end-to-end.

template<int MODE>   // 0: degree (xv=1)   1: layer (gather V bf16)
__global__ __launch_bounds__(256) void agg_k(const float* __restrict__ ea, const float* __restrict__ W1,
                                             const float* __restrict__ W2, const int* __restrict__ perm,
                                             const int* __restrict__ srcs, const int* __restrict__ tgts,
                                             const u16* __restrict__ V, float* __restrict__ U, int E){
  __shared__ __align__(16) u16 stage[EPB*ST];   // t1 (bf16) then ew (bf16), wave-local rows
  __shared__ __align__(16) u16 w2s[64*ST];      // W2[n][k] bf16
  __shared__ __align__(16) u16 w1s[64*32];      // W1[n][k] bf16, k zero-padded 8->32
  __shared__ int eid[EPB], sl[EPB], tl[EPB];
  int tid = threadIdx.x;
  int j0 = blockIdx.x*EPB;

  if (tid < EPB){
    int j = j0 + tid;
    bool v = j < E;
    int e = v ? perm[j] : 0;
    eid[tid] = e;
    tl[tid] = v ? tgts[j] : 0;
    if (MODE) sl[tid] = v ? srcs[j] : 0;
  }
  for (int i = tid; i < 2048; i += 256){ int r = i >> 5, k = i & 31; w1s[i] = (k < 8) ? f2b(W1[r*8+k]) : (u16)0; }
  for (int i = tid; i < 4096; i += 256){ w2s[(i>>6)*ST + (i&63)] = f2b(W2[i]); }
  __syncthreads();

  int w = tid >> 6, lane = tid & 63;
  int m16 = lane & 15, quad = lane >> 4;
  int base = w*32;

  // ---- layer 1 via MFMA (K padded 8->32; quads 1-3 hold zeros) ----
  v8bf af1[2];
  #pragma unroll
  for (int mi = 0; mi < 2; mi++){
    af1[mi] = zero8();
    if (quad == 0){
      int el = eid[base + mi*16 + m16];
      const float4* er = (const float4*)(ea + (size_t)el*8);
      af1[mi] = pack8(er[0], er[1]);
    }
  }
  v4f acc1[2][4];
  #pragma unroll
  for (int mi = 0; mi < 2; mi++)
    #pragma unroll
    for (int ni = 0; ni < 4; ni++) acc1[mi][ni] = (v4f){0.f,0.f,0.f,0.f};
  #pragma unroll
  for (int ni = 0; ni < 4; ni++){
    v8bf bf = *(const v8bf*)&w1s[(ni*16 + m16)*32 + quad*8];
    #pragma unroll
    for (int mi = 0; mi < 2; mi++)
      acc1[mi][ni] = __builtin_amdgcn_mfma_f32_16x16x32_bf16(af1[mi], bf, acc1[mi][ni], 0, 0, 0);
  }
  // t1 = relu -> stage (C-layout: row=edge=mi*16+quad*4+r, col=ni*16+m16)
  #pragma unroll
  for (int mi = 0; mi < 2; mi++)
    #pragma unroll
    for (int ni = 0; ni < 4; ni++)
      #pragma unroll
      for (int r = 0; r < 4; r++)
        stage[(base + mi*16 + quad*4 + r)*ST + ni*16 + m16] = f2b(fmaxf(acc1[mi][ni][r], 0.f));

  // ---- layer 2 via MFMA (wave-local; in-order DS makes write->read safe) ----
  v4f acc2[2][4];
  #pragma unroll
  for (int mi = 0; mi < 2; mi++)
    #pragma unroll
    for (int ni = 0; ni < 4; ni++) acc2[mi][ni] = (v4f){0.f,0.f,0.f,0.f};
  #pragma unroll
  for (int ks = 0; ks < 2; ks++){
    v8bf bf[4];
    #pragma unroll
    for (int ni = 0; ni < 4; ni++)
      bf[ni] = *(const v8bf*)&w2s[(ni*16 + m16)*ST + ks*32 + quad*8];
    #pragma unroll
    for (int mi = 0; mi < 2; mi++){
      v8bf af = *(const v8bf*)&stage[(base + mi*16 + m16)*ST + ks*32 + quad*8];
      #pragma unroll
      for (int ni = 0; ni < 4; ni++)
        acc2[mi][ni] = __builtin_amdgcn_mfma_f32_16x16x32_bf16(af, bf[ni], acc2[mi][ni], 0, 0, 0);
    }
  }
  // ew = relu -> stage
  #pragma unroll
  for (int mi = 0; mi < 2; mi++)
    #pragma unroll
    for (int ni = 0; ni < 4; ni++)
      #pragma unroll
      for (int r = 0; r < 4; r++)
        stage[(base + mi*16 + quad*4 + r)*ST + ni*16 + m16] = f2b(fmaxf(acc2[mi][ni][r], 0.f));

  // ---- segmented scan over this wave's 32 sorted edges; lane = channel ----
  int lim = E - (j0 + base); if (lim > 32) lim = 32;
  if (lim == 32){
    float s = 0.f;
    int cur = tl[base];
    #pragma unroll
    for (int q0 = 0; q0 < 32; q0 += 8){
      float wv[8], xv[8];
      #pragma unroll
      for (int q = 0; q < 8; q++){
        wv[q] = b2f(stage[(base+q0+q)*ST + lane]);
        xv[q] = MODE ? b2f(V[(size_t)sl[base+q0+q]*64 + lane]) : 1.f;
      }
      #pragma unroll
      for (int q = 0; q < 8; q++){
        int t = tl[base+q0+q];
        if (t != cur){ atomicAdd(&U[(size_t)cur*64 + lane], s); s = 0.f; cur = t; }
        s += wv[q]*xv[q];
      }
    }
    atomicAdd(&U[(size_t)cur*64 + lane], s);
  } else if (lim > 0){
    float s = 0.f;
    int cur = tl[base];
    for (int q = 0; q < lim; q++){
      float wv = b2f(stage[(base+q)*ST + lane]);
      float xv = MODE ? b2f(V[(size_t)sl[base+q]*64 + lane]) : 1.f;
      int t = tl[base+q];
      if (t != cur){ atomicAdd(&U[(size_t)cur*64 + lane], s); s = 0.f; cur = t; }
      s += wv*xv;
    }
    atomicAdd(&U[(size_t)cur*64 + lane], s);
  }
}

__global__ __launch_bounds__(256) void degfin_k(float* __restrict__ U, float* __restrict__ dinv, int NH){
  int i = blockIdx.x*256 + threadIdx.x;
  if (i < NH){
    dinv[i] = rsqrtf(1.f + U[i]);
    U[i] = 0.f;
  }
}

// ---------------- x_ = x@Wi^T + bi ; V0 = bf16(dinv*relu(x_)*wconv0) — 16 nodes/block ----------

__global__ __launch_bounds__(256) void xlin_k(const float* __restrict__ x, const float* __restrict__ Wi,
                                              const float* __restrict__ bi, const float* __restrict__ wconv0,
                                              const float* __restrict__ dinv,
                                              float* __restrict__ xlin, u16* __restrict__ V, int N){
  __shared__ float wt[128*64];   // WiT[k][o]
  __shared__ float xs[16][128];
  int tid = threadIdx.x;
  for (int i = tid; i < 8192; i += 256){ int o = i >> 7, k = i & 127; wt[k*64+o] = Wi[i]; }
  int nb0 = blockIdx.x*16;
  for (int i = tid; i < 2048; i += 256){
    int nn = i >> 7, k = i & 127; int n = nb0 + nn;
    xs[nn][k] = (n < N) ? x[(size_t)n*128 + k] : 0.f;
  }
  __syncthreads();
  int w = tid >> 6, lane = tid & 63;
  for (int nn = w; nn < 16; nn += 4){
    int n = nb0 + nn; if (n >= N) continue;
    float acc = bi[lane];
    #pragma unroll 8
    for (int k = 0; k < 128; k++) acc += xs[nn][k]*wt[k*64+lane];
    xlin[(size_t)n*64 + lane] = acc;
    float v = fmaxf(acc, 0.f) * wconv0[lane] * dinv[(size_t)n*64 + lane];
    V[(size_t)n*64 + lane] = f2b(v);
  }
}

// ---------------- epilogue: conv-finish + mixing + residual (+ fused output) — 16 nodes/block ----

__global__ __launch_bounds__(256) void epi_k(const float* __restrict__ xlin, const float* __restrict__ dinv,
                                             float* __restrict__ U, u16* __restrict__ V,
                                             const float* __restrict__ Wl, const float* __restrict__ bconv,
                                             const float* __restrict__ wconv_next, const float* __restrict__ Wo,
                                             float* __restrict__ out, int N, int last){
  __shared__ float wt[128*64];   // WlT[c][o]
  __shared__ float gs[16][64];
  __shared__ float xls[16][64];
  int tid = threadIdx.x;
  for (int i = tid; i < 8192; i += 256){ int o = i >> 7, c = i & 127; wt[c*64+o] = Wl[i]; }
  int nb0 = blockIdx.x*16;
  for (int i = tid; i < 1024; i += 256){
    int nn = i >> 6, c = i & 63; int n = nb0 + nn;
    if (n < N){
      size_t idx = (size_t)n*64 + c;
      xls[nn][c] = xlin[idx];
      gs[nn][c]  = dinv[idx]*(b2f(V[idx]) + U[idx]) + bconv[c];
    }
  }
  __syncthreads();
  int w = tid >> 6, lane = tid & 63;
  for (int nn = w; nn < 16; nn += 4){
    int n = nb0 + nn; if (n >= N) continue;
    float h = xls[nn][lane];
    #pragma unroll 8
    for (int k = 0; k < 64; k++) h += xls[nn][k]*wt[k*64+lane];
    #pragma unroll 8
    for (int k = 0; k < 64; k++) h += gs[nn][k]*wt[(64+k)*64+lane];
    float r = fmaxf(h, 0.f);
    size_t idx = (size_t)n*64 + lane;
    if (!last){
      V[idx] = f2b(r * wconv_next[lane] * dinv[idx]);
      U[idx] = 0.f;
    } else {
      float v = xls[nn][lane]*Wo[lane] + r*Wo[64 + lane];
      #pragma unroll
      for (int off = 32; off > 0; off >>= 1) v += __shfl_down(v, off, 64);
      if (lane == 0) out[n] = v;
    }
  }
}

extern "C" void kernel_launch(void* const* d_in, const int* in_sizes, int n_in,
                              void* d_out, int out_size, void* d_ws, size_t ws_size,
                              hipStream_t stream){
  const float* x     = (const float*)d_in[0];
  const int*   ei    = (const int*)  d_in[1];
  const float* ea    = (const float*)d_in[2];
  const float* W1    = (const float*)d_in[3];
  const float* W2    = (const float*)d_in[4];
  const float* Wi    = (const float*)d_in[5];
  const float* bi    = (const float*)d_in[6];
  const float* wconv = (const float*)d_in[7];
  const float* bconv = (const float*)d_in[8];
  const float* Wl    = (const float*)d_in[9];
  const float* Wo    = (const float*)d_in[10];
  float* out = (float*)d_out;

  int N = in_sizes[0] / 128;
  int E = in_sizes[2] / 8;
  const int* row = ei;
  const int* col = ei + E;

  char* p = (char*)d_ws;
  auto alloc = [&](size_t nbytes){ char* r = p; p += (nbytes + 255) & ~(size_t)255; return r; };

  int*   counts = (int*)  alloc((size_t)N*4);
  int*   start  = (int*)  alloc((size_t)(N+1)*4);
  int*   cursor = (int*)  alloc((size_t)N*4);
  int*   bsum   = (int*)  alloc(4096);
  int*   perm   = (int*)  alloc((size_t)E*4);
  int*   srcs   = (int*)  alloc((size_t)E*4);
  int*   tgts   = (int*)  alloc((size_t)E*4);
  float* U      = (float*)alloc((size_t)N*256);
  float* dinv   = (float*)alloc((size_t)N*256);
  float* xlin   = (float*)alloc((size_t)N*256);
  u16*   V      = (u16*)  alloc((size_t)N*128);

  int gE   = (E + 255) / 256;
  int gA   = (E + EPB - 1) / EPB;
  int nb1  = (N + 1023) / 1024;
  int gN4  = (N + 3) / 4;
  int gN16 = (N + 15) / 16;
  int gNH  = (N*64 + 255) / 256;

  hipMemsetAsync(counts, 0, (size_t)N*4, stream);
  hipMemsetAsync(U, 0, (size_t)N*256, stream);

  hist_k <<<gE, 256, 0, stream>>>(col, counts, E);
  scan1_k<<<nb1, 1024, 0, stream>>>(counts, start, bsum, N);
  scan2_k<<<1, 1024, 0, stream>>>(bsum, nb1, start, N, E);
  scan3_k<<<nb1, 1024, 0, stream>>>(start, bsum, cursor, N);
  scat_k <<<gE, 256, 0, stream>>>(col, cursor, perm, E);
  fill_k <<<gE, 256, 0, stream>>>(row, perm, srcs, E);
  tgt_k  <<<gN4, 256, 0, stream>>>(start, tgts, N);

  agg_k<0><<<gA, 256, 0, stream>>>(ea, W1, W2, perm, srcs, tgts, V, U, E);   // degree
  degfin_k<<<gNH, 256, 0, stream>>>(U, dinv, N*64);
  xlin_k  <<<gN16, 256, 0, stream>>>(x, Wi, bi, wconv, dinv, xlin, V, N);

  agg_k<1><<<gA, 256, 0, stream>>>(ea, W1, W2, perm, srcs, tgts, V, U, E);
  epi_k   <<<gN16, 256, 0, stream>>>(xlin, dinv, U, V, Wl + 0*8192, bconv +   0, wconv +  64, Wo, out, N, 0);
  agg_k<1><<<gA, 256, 0, stream>>>(ea, W1, W2, perm, srcs, tgts, V, U, E);
  epi_k   <<<gN16, 256, 0, stream>>>(xlin, dinv, U, V, Wl + 1*8192, bconv +  64, wconv + 128, Wo, out, N, 0);
  agg_k<1><<<gA, 256, 0, stream>>>(ea, W1, W2, perm, srcs, tgts, V, U, E);
  epi_k   <<<gN16, 256, 0, stream>>>(xlin, dinv, U, V, Wl + 2*8192, bconv + 128, wconv      , Wo, out, N, 1);
}

// Round 5
// 950.262 us; speedup vs baseline: 4.3099x; 1.5262x over previous
//
#include <hip/hip_runtime.h>

using u16 = unsigned short;
using u32 = unsigned int;

typedef __bf16 v8bf __attribute__((ext_vector_type(8)));
typedef float  v4f  __attribute__((ext_vector_type(4)));

#define ST  68    // u16 stride for agg stage rows
#define STK 132   // u16 stride for 128-wide bf16 LDS rows (66 dwords: ~2-way max on b128 reads)
#define EPB 128   // edges per block in agg_k

__device__ __forceinline__ u16 f2b(float f){
  u32 u = __builtin_bit_cast(u32, f);
  u += 0x7FFFu + ((u >> 16) & 1u);
  return (u16)(u >> 16);
}
__device__ __forceinline__ float b2f(u16 b){
  u32 u = ((u32)b) << 16;
  return __builtin_bit_cast(float, u);
}

union bfu { v8bf v; u16 s[8]; };

__device__ __forceinline__ v8bf zero8(){
  bfu u;
  #pragma unroll
  for (int i = 0; i < 8; i++) u.s[i] = 0;
  return u.v;
}
__device__ __forceinline__ v8bf pack8(float4 a, float4 b){
  bfu u;
  u.s[0]=f2b(a.x); u.s[1]=f2b(a.y); u.s[2]=f2b(a.z); u.s[3]=f2b(a.w);
  u.s[4]=f2b(b.x); u.s[5]=f2b(b.y); u.s[6]=f2b(b.z); u.s[7]=f2b(b.w);
  return u.v;
}

// ---------------- counting sort by target ----------------

__global__ __launch_bounds__(256) void hist_k(const int* __restrict__ col, int* __restrict__ counts, int E){
  int e = blockIdx.x*256 + threadIdx.x;
  if (e < E) atomicAdd(&counts[col[e]], 1);
}

__global__ __launch_bounds__(1024) void scan1_k(const int* __restrict__ counts, int* __restrict__ start,
                                                int* __restrict__ bsum, int N){
  __shared__ int s[1024];
  int tid = threadIdx.x;
  int i = blockIdx.x*1024 + tid;
  int v = (i < N) ? counts[i] : 0;
  s[tid] = v; __syncthreads();
  for (int off = 1; off < 1024; off <<= 1){
    int t = (tid >= off) ? s[tid-off] : 0;
    __syncthreads();
    s[tid] += t;
    __syncthreads();
  }
  if (i < N) start[i] = s[tid] - v;
  if (tid == 1023) bsum[blockIdx.x] = s[1023];
}

__global__ __launch_bounds__(1024) void scan2_k(int* __restrict__ bsum, int nb, int* __restrict__ start,
                                                int N, int E){
  __shared__ int s[1024];
  int tid = threadIdx.x;
  int v = (tid < nb) ? bsum[tid] : 0;
  s[tid] = v; __syncthreads();
  for (int off = 1; off < 1024; off <<= 1){
    int t = (tid >= off) ? s[tid-off] : 0;
    __syncthreads();
    s[tid] += t;
    __syncthreads();
  }
  if (tid < nb) bsum[tid] = s[tid] - v;
  if (tid == 0) start[N] = E;
}

__global__ __launch_bounds__(1024) void scan3_k(int* __restrict__ start, const int* __restrict__ bsum,
                                                int* __restrict__ cursor, int N){
  int i = blockIdx.x*1024 + threadIdx.x;
  if (i < N){
    int v = start[i] + bsum[blockIdx.x];
    start[i] = v;
    cursor[i] = v;
  }
}

__global__ __launch_bounds__(256) void scat_k(const int* __restrict__ col, int* __restrict__ cursor,
                                              int* __restrict__ perm, int E){
  int e = blockIdx.x*256 + threadIdx.x;
  if (e < E){
    int p = atomicAdd(&cursor[col[e]], 1);
    perm[p] = e;
  }
}

__global__ __launch_bounds__(256) void fill_k(const int* __restrict__ row, const int* __restrict__ perm,
                                              int* __restrict__ srcs, int E){
  int j = blockIdx.x*256 + threadIdx.x;
  if (j < E) srcs[j] = row[perm[j]];
}

__global__ __launch_bounds__(256) void tgt_k(const int* __restrict__ start, int* __restrict__ tgts, int N){
  int w = threadIdx.x >> 6, lane = threadIdx.x & 63;
  int n = blockIdx.x*4 + w;
  if (n >= N) return;
  int e = start[n+1];
  for (int j = start[n] + lane; j < e; j += 64) tgts[j] = n;
}

// ---------------- fused edge-MLP (both layers MFMA) + segmented aggregation ----------------

template<int MODE>   // 0: degree (xv=1)   1: layer (gather V bf16)
__global__ __launch_bounds__(256) void agg_k(const float* __restrict__ ea, const float* __restrict__ W1,
                                             const float* __restrict__ W2, const int* __restrict__ perm,
                                             const int* __restrict__ srcs, const int* __restrict__ tgts,
                                             const u16* __restrict__ V, float* __restrict__ U, int E){
  __shared__ __align__(16) u16 stage[EPB*ST];
  __shared__ __align__(16) u16 w2s[64*ST];
  __shared__ __align__(16) u16 w1s[64*32];
  __shared__ int eid[EPB], sl[EPB], tl[EPB];
  int tid = threadIdx.x;
  int j0 = blockIdx.x*EPB;

  if (tid < EPB){
    int j = j0 + tid;
    bool v = j < E;
    int e = v ? perm[j] : 0;
    eid[tid] = e;
    tl[tid] = v ? tgts[j] : 0;
    if (MODE) sl[tid] = v ? srcs[j] : 0;
  }
  for (int i = tid; i < 2048; i += 256){ int r = i >> 5, k = i & 31; w1s[i] = (k < 8) ? f2b(W1[r*8+k]) : (u16)0; }
  for (int i = tid; i < 4096; i += 256){ w2s[(i>>6)*ST + (i&63)] = f2b(W2[i]); }
  __syncthreads();

  int w = tid >> 6, lane = tid & 63;
  int m16 = lane & 15, quad = lane >> 4;
  int base = w*32;

  // layer 1 via MFMA (K padded 8->32)
  v8bf af1[2];
  #pragma unroll
  for (int mi = 0; mi < 2; mi++){
    af1[mi] = zero8();
    if (quad == 0){
      int el = eid[base + mi*16 + m16];
      const float4* er = (const float4*)(ea + (size_t)el*8);
      af1[mi] = pack8(er[0], er[1]);
    }
  }
  v4f acc1[2][4];
  #pragma unroll
  for (int mi = 0; mi < 2; mi++)
    #pragma unroll
    for (int ni = 0; ni < 4; ni++) acc1[mi][ni] = (v4f){0.f,0.f,0.f,0.f};
  #pragma unroll
  for (int ni = 0; ni < 4; ni++){
    v8bf bf = *(const v8bf*)&w1s[(ni*16 + m16)*32 + quad*8];
    #pragma unroll
    for (int mi = 0; mi < 2; mi++)
      acc1[mi][ni] = __builtin_amdgcn_mfma_f32_16x16x32_bf16(af1[mi], bf, acc1[mi][ni], 0, 0, 0);
  }
  #pragma unroll
  for (int mi = 0; mi < 2; mi++)
    #pragma unroll
    for (int ni = 0; ni < 4; ni++)
      #pragma unroll
      for (int r = 0; r < 4; r++)
        stage[(base + mi*16 + quad*4 + r)*ST + ni*16 + m16] = f2b(fmaxf(acc1[mi][ni][r], 0.f));

  // layer 2 via MFMA (wave-local)
  v4f acc2[2][4];
  #pragma unroll
  for (int mi = 0; mi < 2; mi++)
    #pragma unroll
    for (int ni = 0; ni < 4; ni++) acc2[mi][ni] = (v4f){0.f,0.f,0.f,0.f};
  #pragma unroll
  for (int ks = 0; ks < 2; ks++){
    v8bf bf[4];
    #pragma unroll
    for (int ni = 0; ni < 4; ni++)
      bf[ni] = *(const v8bf*)&w2s[(ni*16 + m16)*ST + ks*32 + quad*8];
    #pragma unroll
    for (int mi = 0; mi < 2; mi++){
      v8bf af = *(const v8bf*)&stage[(base + mi*16 + m16)*ST + ks*32 + quad*8];
      #pragma unroll
      for (int ni = 0; ni < 4; ni++)
        acc2[mi][ni] = __builtin_amdgcn_mfma_f32_16x16x32_bf16(af, bf[ni], acc2[mi][ni], 0, 0, 0);
    }
  }
  #pragma unroll
  for (int mi = 0; mi < 2; mi++)
    #pragma unroll
    for (int ni = 0; ni < 4; ni++)
      #pragma unroll
      for (int r = 0; r < 4; r++)
        stage[(base + mi*16 + quad*4 + r)*ST + ni*16 + m16] = f2b(fmaxf(acc2[mi][ni][r], 0.f));

  // segmented scan over this wave's 32 sorted edges
  int lim = E - (j0 + base); if (lim > 32) lim = 32;
  if (lim == 32){
    float s = 0.f;
    int cur = tl[base];
    #pragma unroll
    for (int q0 = 0; q0 < 32; q0 += 8){
      float wv[8], xv[8];
      #pragma unroll
      for (int q = 0; q < 8; q++){
        wv[q] = b2f(stage[(base+q0+q)*ST + lane]);
        xv[q] = MODE ? b2f(V[(size_t)sl[base+q0+q]*64 + lane]) : 1.f;
      }
      #pragma unroll
      for (int q = 0; q < 8; q++){
        int t = tl[base+q0+q];
        if (t != cur){ atomicAdd(&U[(size_t)cur*64 + lane], s); s = 0.f; cur = t; }
        s += wv[q]*xv[q];
      }
    }
    atomicAdd(&U[(size_t)cur*64 + lane], s);
  } else if (lim > 0){
    float s = 0.f;
    int cur = tl[base];
    for (int q = 0; q < lim; q++){
      float wv = b2f(stage[(base+q)*ST + lane]);
      float xv = MODE ? b2f(V[(size_t)sl[base+q]*64 + lane]) : 1.f;
      int t = tl[base+q];
      if (t != cur){ atomicAdd(&U[(size_t)cur*64 + lane], s); s = 0.f; cur = t; }
      s += wv*xv;
    }
    atomicAdd(&U[(size_t)cur*64 + lane], s);
  }
}

__global__ __launch_bounds__(256) void degfin_k(float* __restrict__ U, float* __restrict__ dinv, int NH){
  int i = blockIdx.x*256 + threadIdx.x;
  if (i < NH){
    dinv[i] = rsqrtf(1.f + U[i]);
    U[i] = 0.f;
  }
}

// ---------------- xlin via MFMA: 64 nodes/block ----------------

__global__ __launch_bounds__(256) void xlin_k(const float* __restrict__ x, const float* __restrict__ Wi,
                                              const float* __restrict__ bi, const float* __restrict__ wconv0,
                                              const float* __restrict__ dinv,
                                              float* __restrict__ xlin, u16* __restrict__ V, int N){
  __shared__ __align__(16) u16 wb[64*STK];   // Wi bf16 [o][k]
  __shared__ __align__(16) u16 as[64*STK];   // x  bf16 [node][k]
  int tid = threadIdx.x;
  for (int i = tid; i < 8192; i += 256){ int o = i >> 7, k = i & 127; wb[o*STK+k] = f2b(Wi[i]); }
  int nb0 = blockIdx.x*64;
  for (int i = tid; i < 8192; i += 256){
    int nn = i >> 7, k = i & 127; int n = nb0 + nn;
    as[nn*STK+k] = (n < N) ? f2b(x[(size_t)n*128 + k]) : (u16)0;
  }
  __syncthreads();
  int w = tid >> 6, lane = tid & 63;
  int m16 = lane & 15, quad = lane >> 4;
  int wbase = w*16;
  v8bf af[4];
  #pragma unroll
  for (int ks = 0; ks < 4; ks++) af[ks] = *(const v8bf*)&as[(wbase+m16)*STK + ks*32 + quad*8];
  v4f acc[4];
  #pragma unroll
  for (int ni = 0; ni < 4; ni++) acc[ni] = (v4f){0.f,0.f,0.f,0.f};
  #pragma unroll
  for (int ks = 0; ks < 4; ks++){
    #pragma unroll
    for (int ni = 0; ni < 4; ni++){
      v8bf bf = *(const v8bf*)&wb[(ni*16+m16)*STK + ks*32 + quad*8];
      acc[ni] = __builtin_amdgcn_mfma_f32_16x16x32_bf16(af[ks], bf, acc[ni], 0, 0, 0);
    }
  }
  #pragma unroll
  for (int ni = 0; ni < 4; ni++){
    int c = ni*16 + m16;
    float wc = wconv0[c], bc = bi[c];
    #pragma unroll
    for (int r = 0; r < 4; r++){
      int n = nb0 + wbase + quad*4 + r;
      if (n < N){
        float val = acc[ni][r] + bc;
        size_t idx = (size_t)n*64 + c;
        xlin[idx] = val;
        V[idx] = f2b(fmaxf(val, 0.f) * wc * dinv[idx]);
      }
    }
  }
}

// ---------------- epilogue via MFMA: residual folded as identity in Wl ----------------

__global__ __launch_bounds__(256) void epi_k(const float* __restrict__ xlin, const float* __restrict__ dinv,
                                             float* __restrict__ U, u16* __restrict__ V,
                                             const float* __restrict__ Wl, const float* __restrict__ bconv,
                                             const float* __restrict__ wconv_next, const float* __restrict__ Wo,
                                             float* __restrict__ out, int N, int last){
  __shared__ __align__(16) u16 wb[64*STK];   // (Wl + [I|0]) bf16 [o][c]
  __shared__ __align__(16) u16 an[64*STK];   // concat(x_, g) bf16 [node][c]
  int tid = threadIdx.x;
  for (int i = tid; i < 8192; i += 256){
    int o = i >> 7, c = i & 127;
    wb[o*STK+c] = f2b(Wl[i] + ((c == o) ? 1.f : 0.f));
  }
  int nb0 = blockIdx.x*64;
  for (int i = tid; i < 4096; i += 256){
    int nn = i >> 6, c = i & 63; int n = nb0 + nn;
    u16 xb = 0, gb = 0;
    if (n < N){
      size_t idx = (size_t)n*64 + c;
      float xl = xlin[idx];
      float g  = dinv[idx]*(b2f(V[idx]) + U[idx]) + bconv[c];
      xb = f2b(xl); gb = f2b(g);
      if (!last) U[idx] = 0.f;
    }
    an[nn*STK + c] = xb;
    an[nn*STK + 64 + c] = gb;
  }
  __syncthreads();
  int w = tid >> 6, lane = tid & 63;
  int m16 = lane & 15, quad = lane >> 4;
  int wbase = w*16;
  v8bf af[4];
  #pragma unroll
  for (int ks = 0; ks < 4; ks++) af[ks] = *(const v8bf*)&an[(wbase+m16)*STK + ks*32 + quad*8];
  v4f acc[4];
  #pragma unroll
  for (int ni = 0; ni < 4; ni++) acc[ni] = (v4f){0.f,0.f,0.f,0.f};
  #pragma unroll
  for (int ks = 0; ks < 4; ks++){
    #pragma unroll
    for (int ni = 0; ni < 4; ni++){
      v8bf bf = *(const v8bf*)&wb[(ni*16+m16)*STK + ks*32 + quad*8];
      acc[ni] = __builtin_amdgcn_mfma_f32_16x16x32_bf16(af[ks], bf, acc[ni], 0, 0, 0);
    }
  }
  if (!last){
    #pragma unroll
    for (int ni = 0; ni < 4; ni++){
      int c = ni*16 + m16;
      float wc = wconv_next[c];
      #pragma unroll
      for (int r = 0; r < 4; r++){
        int n = nb0 + wbase + quad*4 + r;
        if (n < N){
          size_t idx = (size_t)n*64 + c;
          V[idx] = f2b(fmaxf(acc[ni][r], 0.f) * wc * dinv[idx]);
        }
      }
    }
  } else {
    float part[4];
    #pragma unroll
    for (int r = 0; r < 4; r++){
      float p = 0.f;
      int rowl = wbase + quad*4 + r;
      #pragma unroll
      for (int ni = 0; ni < 4; ni++){
        int c = ni*16 + m16;
        float xl = b2f(an[rowl*STK + c]);
        float hr = fmaxf(acc[ni][r], 0.f);
        p += xl*Wo[c] + hr*Wo[64 + c];
      }
      part[r] = p;
    }
    #pragma unroll
    for (int off = 1; off < 16; off <<= 1)
      #pragma unroll
      for (int r = 0; r < 4; r++) part[r] += __shfl_xor(part[r], off, 64);
    if (m16 == 0){
      #pragma unroll
      for (int r = 0; r < 4; r++){
        int n = nb0 + wbase + quad*4 + r;
        if (n < N) out[n] = part[r];
      }
    }
  }
}

extern "C" void kernel_launch(void* const* d_in, const int* in_sizes, int n_in,
                              void* d_out, int out_size, void* d_ws, size_t ws_size,
                              hipStream_t stream){
  const float* x     = (const float*)d_in[0];
  const int*   ei    = (const int*)  d_in[1];
  const float* ea    = (const float*)d_in[2];
  const float* W1    = (const float*)d_in[3];
  const float* W2    = (const float*)d_in[4];
  const float* Wi    = (const float*)d_in[5];
  const float* bi    = (const float*)d_in[6];
  const float* wconv = (const float*)d_in[7];
  const float* bconv = (const float*)d_in[8];
  const float* Wl    = (const float*)d_in[9];
  const float* Wo    = (const float*)d_in[10];
  float* out = (float*)d_out;

  int N = in_sizes[0] / 128;
  int E = in_sizes[2] / 8;
  const int* row = ei;
  const int* col = ei + E;

  char* p = (char*)d_ws;
  auto alloc = [&](size_t nbytes){ char* r = p; p += (nbytes + 255) & ~(size_t)255; return r; };

  int*   counts = (int*)  alloc((size_t)N*4);
  int*   start  = (int*)  alloc((size_t)(N+1)*4);
  int*   cursor = (int*)  alloc((size_t)N*4);
  int*   bsum   = (int*)  alloc(4096);
  int*   perm   = (int*)  alloc((size_t)E*4);
  int*   srcs   = (int*)  alloc((size_t)E*4);
  int*   tgts   = (int*)  alloc((size_t)E*4);
  float* U      = (float*)alloc((size_t)N*256);
  float* dinv   = (float*)alloc((size_t)N*256);
  float* xlin   = (float*)alloc((size_t)N*256);
  u16*   V      = (u16*)  alloc((size_t)N*128);

  int gE   = (E + 255) / 256;
  int gA   = (E + EPB - 1) / EPB;
  int nb1  = (N + 1023) / 1024;
  int gN4  = (N + 3) / 4;
  int gN64 = (N + 63) / 64;
  int gNH  = (N*64 + 255) / 256;

  hipMemsetAsync(counts, 0, (size_t)N*4, stream);
  hipMemsetAsync(U, 0, (size_t)N*256, stream);

  hist_k <<<gE, 256, 0, stream>>>(col, counts, E);
  scan1_k<<<nb1, 1024, 0, stream>>>(counts, start, bsum, N);
  scan2_k<<<1, 1024, 0, stream>>>(bsum, nb1, start, N, E);
  scan3_k<<<nb1, 1024, 0, stream>>>(start, bsum, cursor, N);
  scat_k <<<gE, 256, 0, stream>>>(col, cursor, perm, E);
  fill_k <<<gE, 256, 0, stream>>>(row, perm, srcs, E);
  tgt_k  <<<gN4, 256, 0, stream>>>(start, tgts, N);

  agg_k<0><<<gA, 256, 0, stream>>>(ea, W1, W2, perm, srcs, tgts, V, U, E);   // degree
  degfin_k<<<gNH, 256, 0, stream>>>(U, dinv, N*64);
  xlin_k  <<<gN64, 256, 0, stream>>>(x, Wi, bi, wconv, dinv, xlin, V, N);

  agg_k<1><<<gA, 256, 0, stream>>>(ea, W1, W2, perm, srcs, tgts, V, U, E);
  epi_k   <<<gN64, 256, 0, stream>>>(xlin, dinv, U, V, Wl + 0*8192, bconv +   0, wconv +  64, Wo, out, N, 0);
  agg_k<1><<<gA, 256, 0, stream>>>(ea, W1, W2, perm, srcs, tgts, V, U, E);
  epi_k   <<<gN64, 256, 0, stream>>>(xlin, dinv, U, V, Wl + 1*8192, bconv +  64, wconv + 128, Wo, out, N, 0);
  agg_k<1><<<gA, 256, 0, stream>>>(ea, W1, W2, perm, srcs, tgts, V, U, E);
  epi_k   <<<gN64, 256, 0, stream>>>(xlin, dinv, U, V, Wl + 2*8192, bconv + 128, wconv      , Wo, out, N, 1);
}

// Round 6
// 827.006 us; speedup vs baseline: 4.9522x; 1.1490x over previous
//
#include <hip/hip_runtime.h>

using u16 = unsigned short;
using u32 = unsigned int;

typedef __bf16 v8bf __attribute__((ext_vector_type(8)));
typedef float  v4f  __attribute__((ext_vector_type(4)));

#define ST  68    // u16 stride for agg stage rows (34 dwords: 2-way max aliasing)
#define STK 132   // u16 stride for 128-wide bf16 LDS rows
#define EPB 128   // edges per block in agg_k
#define RW  6     // record width in u32: [0..3]=ea bf16x8, [4]=src, [5]=tgt

__device__ __forceinline__ u16 f2b(float f){
  u32 u = __builtin_bit_cast(u32, f);
  u += 0x7FFFu + ((u >> 16) & 1u);
  return (u16)(u >> 16);
}
__device__ __forceinline__ float b2f(u16 b){
  u32 u = ((u32)b) << 16;
  return __builtin_bit_cast(float, u);
}
__device__ __forceinline__ u32 pk2(float lo, float hi){
  return ((u32)f2b(hi) << 16) | f2b(lo);
}

union bfu { v8bf v; u16 s[8]; u32 w[4]; };

__device__ __forceinline__ v8bf zero8(){
  bfu u;
  #pragma unroll
  for (int i = 0; i < 4; i++) u.w[i] = 0;
  return u.v;
}

// ---------------- counting sort by target ----------------

__global__ __launch_bounds__(256) void hist_k(const int* __restrict__ col, int* __restrict__ counts, int E){
  int e = blockIdx.x*256 + threadIdx.x;
  if (e < E) atomicAdd(&counts[col[e]], 1);
}

__global__ __launch_bounds__(1024) void scan1_k(const int* __restrict__ counts, int* __restrict__ start,
                                                int* __restrict__ bsum, int N){
  __shared__ int s[1024];
  int tid = threadIdx.x;
  int i = blockIdx.x*1024 + tid;
  int v = (i < N) ? counts[i] : 0;
  s[tid] = v; __syncthreads();
  for (int off = 1; off < 1024; off <<= 1){
    int t = (tid >= off) ? s[tid-off] : 0;
    __syncthreads();
    s[tid] += t;
    __syncthreads();
  }
  if (i < N) start[i] = s[tid] - v;
  if (tid == 1023) bsum[blockIdx.x] = s[1023];
}

__global__ __launch_bounds__(1024) void scan2_k(int* __restrict__ bsum, int nb, int* __restrict__ start,
                                                int N, int E){
  __shared__ int s[1024];
  int tid = threadIdx.x;
  int v = (tid < nb) ? bsum[tid] : 0;
  s[tid] = v; __syncthreads();
  for (int off = 1; off < 1024; off <<= 1){
    int t = (tid >= off) ? s[tid-off] : 0;
    __syncthreads();
    s[tid] += t;
    __syncthreads();
  }
  if (tid < nb) bsum[tid] = s[tid] - v;
  if (tid == 0) start[N] = E;
}

__global__ __launch_bounds__(1024) void scan3_k(int* __restrict__ start, const int* __restrict__ bsum,
                                                int* __restrict__ cursor, int N){
  int i = blockIdx.x*1024 + threadIdx.x;
  if (i < N){
    int v = start[i] + bsum[blockIdx.x];
    start[i] = v;
    cursor[i] = v;
  }
}

// fused scatter: one 24B record per edge {ea bf16x8, src, tgt} into sorted slot
__global__ __launch_bounds__(256) void scat_k(const int* __restrict__ row, const int* __restrict__ col,
                                              const float* __restrict__ ea, int* __restrict__ cursor,
                                              u32* __restrict__ rec, int E){
  int e = blockIdx.x*256 + threadIdx.x;
  if (e < E){
    int c = col[e];
    int s = row[e];
    const float4* eap = (const float4*)(ea + (size_t)e*8);
    float4 a0 = eap[0], a1 = eap[1];
    u32 w0 = pk2(a0.x, a0.y), w1 = pk2(a0.z, a0.w);
    u32 w2 = pk2(a1.x, a1.y), w3 = pk2(a1.z, a1.w);
    int p = atomicAdd(&cursor[c], 1);
    int2* r2 = (int2*)(rec + (size_t)p*RW);   // 8B aligned (24B stride)
    r2[0] = make_int2((int)w0, (int)w1);
    r2[1] = make_int2((int)w2, (int)w3);
    r2[2] = make_int2(s, c);
  }
}

// ---------------- fused edge-MLP (both layers MFMA) + segmented aggregation ----------------

template<int MODE>   // 0: degree (xv=1)   1: layer (gather V bf16)
__global__ __launch_bounds__(256) void agg_k(const u32* __restrict__ rec, const float* __restrict__ W1,
                                             const float* __restrict__ W2,
                                             const u16* __restrict__ V, float* __restrict__ U, int E){
  __shared__ __align__(16) u16 stage[EPB*ST];   // ea (pre-barrier) -> t1 -> ew, per-edge rows
  __shared__ __align__(16) u16 w2s[64*ST];
  __shared__ __align__(16) u16 w1s[64*32];
  __shared__ int sl[EPB], tl[EPB];
  int tid = threadIdx.x;
  int j0 = blockIdx.x*EPB;

  if (tid < EPB){
    int j = j0 + tid;
    int2 a = make_int2(0,0), b = make_int2(0,0), c = make_int2(0,0);
    if (j < E){
      const int2* r2 = (const int2*)(rec + (size_t)j*RW);
      a = r2[0]; b = r2[1]; c = r2[2];
    }
    sl[tid] = c.x;
    tl[tid] = c.y;
    *(int2*)&stage[tid*ST]     = a;
    *(int2*)&stage[tid*ST + 4] = b;
  }
  for (int i = tid; i < 2048; i += 256){ int r = i >> 5, k = i & 31; w1s[i] = (k < 8) ? f2b(W1[r*8+k]) : (u16)0; }
  for (int i = tid; i < 4096; i += 256){ w2s[(i>>6)*ST + (i&63)] = f2b(W2[i]); }
  __syncthreads();

  int w = tid >> 6, lane = tid & 63;
  int m16 = lane & 15, quad = lane >> 4;
  int base = w*32;

  // layer 1 via MFMA (K padded 8->32; quads 1-3 zero)
  v8bf af1[2];
  #pragma unroll
  for (int mi = 0; mi < 2; mi++){
    af1[mi] = zero8();
    if (quad == 0){
      int rr = base + mi*16 + m16;
      int2 p0 = *(const int2*)&stage[rr*ST];
      int2 p1 = *(const int2*)&stage[rr*ST + 4];
      bfu u; u.w[0] = (u32)p0.x; u.w[1] = (u32)p0.y; u.w[2] = (u32)p1.x; u.w[3] = (u32)p1.y;
      af1[mi] = u.v;
    }
  }
  v4f acc1[2][4];
  #pragma unroll
  for (int mi = 0; mi < 2; mi++)
    #pragma unroll
    for (int ni = 0; ni < 4; ni++) acc1[mi][ni] = (v4f){0.f,0.f,0.f,0.f};
  #pragma unroll
  for (int ni = 0; ni < 4; ni++){
    v8bf bf = *(const v8bf*)&w1s[(ni*16 + m16)*32 + quad*8];
    #pragma unroll
    for (int mi = 0; mi < 2; mi++)
      acc1[mi][ni] = __builtin_amdgcn_mfma_f32_16x16x32_bf16(af1[mi], bf, acc1[mi][ni], 0, 0, 0);
  }
  #pragma unroll
  for (int mi = 0; mi < 2; mi++)
    #pragma unroll
    for (int ni = 0; ni < 4; ni++)
      #pragma unroll
      for (int r = 0; r < 4; r++)
        stage[(base + mi*16 + quad*4 + r)*ST + ni*16 + m16] = f2b(fmaxf(acc1[mi][ni][r], 0.f));

  // layer 2 via MFMA (wave-local rows; per-wave DS ordering makes write->read safe)
  v4f acc2[2][4];
  #pragma unroll
  for (int mi = 0; mi < 2; mi++)
    #pragma unroll
    for (int ni = 0; ni < 4; ni++) acc2[mi][ni] = (v4f){0.f,0.f,0.f,0.f};
  #pragma unroll
  for (int ks = 0; ks < 2; ks++){
    v8bf bf[4];
    #pragma unroll
    for (int ni = 0; ni < 4; ni++)
      bf[ni] = *(const v8bf*)&w2s[(ni*16 + m16)*ST + ks*32 + quad*8];
    #pragma unroll
    for (int mi = 0; mi < 2; mi++){
      v8bf af = *(const v8bf*)&stage[(base + mi*16 + m16)*ST + ks*32 + quad*8];
      #pragma unroll
      for (int ni = 0; ni < 4; ni++)
        acc2[mi][ni] = __builtin_amdgcn_mfma_f32_16x16x32_bf16(af, bf[ni], acc2[mi][ni], 0, 0, 0);
    }
  }
  #pragma unroll
  for (int mi = 0; mi < 2; mi++)
    #pragma unroll
    for (int ni = 0; ni < 4; ni++)
      #pragma unroll
      for (int r = 0; r < 4; r++)
        stage[(base + mi*16 + quad*4 + r)*ST + ni*16 + m16] = f2b(fmaxf(acc2[mi][ni][r], 0.f));

  // segmented scan over this wave's 32 sorted edges; lane = channel
  int lim = E - (j0 + base); if (lim > 32) lim = 32;
  if (lim == 32){
    float s = 0.f;
    int cur = tl[base];
    #pragma unroll
    for (int q0 = 0; q0 < 32; q0 += 8){
      float wv[8], xv[8];
      #pragma unroll
      for (int q = 0; q < 8; q++){
        wv[q] = b2f(stage[(base+q0+q)*ST + lane]);
        xv[q] = MODE ? b2f(V[(size_t)sl[base+q0+q]*64 + lane]) : 1.f;
      }
      #pragma unroll
      for (int q = 0; q < 8; q++){
        int t = tl[base+q0+q];
        if (t != cur){ atomicAdd(&U[(size_t)cur*64 + lane], s); s = 0.f; cur = t; }
        s += wv[q]*xv[q];
      }
    }
    atomicAdd(&U[(size_t)cur*64 + lane], s);
  } else if (lim > 0){
    float s = 0.f;
    int cur = tl[base];
    for (int q = 0; q < lim; q++){
      float wv = b2f(stage[(base+q)*ST + lane]);
      float xv = MODE ? b2f(V[(size_t)sl[base+q]*64 + lane]) : 1.f;
      int t = tl[base+q];
      if (t != cur){ atomicAdd(&U[(size_t)cur*64 + lane], s); s = 0.f; cur = t; }
      s += wv*xv;
    }
    atomicAdd(&U[(size_t)cur*64 + lane], s);
  }
}

__global__ __launch_bounds__(256) void degfin_k(float* __restrict__ U, float* __restrict__ dinv, int NH){
  int i = blockIdx.x*256 + threadIdx.x;
  if (i < NH){
    dinv[i] = rsqrtf(1.f + U[i]);
    U[i] = 0.f;
  }
}

// ---------------- xlin via MFMA: 64 nodes/block; xlin stored bf16 ----------------

__global__ __launch_bounds__(256) void xlin_k(const float* __restrict__ x, const float* __restrict__ Wi,
                                              const float* __restrict__ bi, const float* __restrict__ wconv0,
                                              const float* __restrict__ dinv,
                                              u16* __restrict__ xlin, u16* __restrict__ V, int N){
  __shared__ __align__(16) u16 wb[64*STK];   // Wi bf16 [o][k]
  __shared__ __align__(16) u16 as[64*STK];   // x  bf16 [node][k]
  int tid = threadIdx.x;
  for (int i = tid; i < 8192; i += 256){ int o = i >> 7, k = i & 127; wb[o*STK+k] = f2b(Wi[i]); }
  int nb0 = blockIdx.x*64;
  for (int i = tid; i < 8192; i += 256){
    int nn = i >> 7, k = i & 127; int n = nb0 + nn;
    as[nn*STK+k] = (n < N) ? f2b(x[(size_t)n*128 + k]) : (u16)0;
  }
  __syncthreads();
  int w = tid >> 6, lane = tid & 63;
  int m16 = lane & 15, quad = lane >> 4;
  int wbase = w*16;
  v8bf af[4];
  #pragma unroll
  for (int ks = 0; ks < 4; ks++) af[ks] = *(const v8bf*)&as[(wbase+m16)*STK + ks*32 + quad*8];
  v4f acc[4];
  #pragma unroll
  for (int ni = 0; ni < 4; ni++) acc[ni] = (v4f){0.f,0.f,0.f,0.f};
  #pragma unroll
  for (int ks = 0; ks < 4; ks++){
    #pragma unroll
    for (int ni = 0; ni < 4; ni++){
      v8bf bf = *(const v8bf*)&wb[(ni*16+m16)*STK + ks*32 + quad*8];
      acc[ni] = __builtin_amdgcn_mfma_f32_16x16x32_bf16(af[ks], bf, acc[ni], 0, 0, 0);
    }
  }
  #pragma unroll
  for (int ni = 0; ni < 4; ni++){
    int c = ni*16 + m16;
    float wc = wconv0[c], bc = bi[c];
    #pragma unroll
    for (int r = 0; r < 4; r++){
      int n = nb0 + wbase + quad*4 + r;
      if (n < N){
        float val = acc[ni][r] + bc;
        size_t idx = (size_t)n*64 + c;
        xlin[idx] = f2b(val);
        V[idx] = f2b(fmaxf(val, 0.f) * wc * dinv[idx]);
      }
    }
  }
}

// ---------------- epilogue via MFMA: residual folded as identity in Wl ----------------

__global__ __launch_bounds__(256) void epi_k(const u16* __restrict__ xlin, const float* __restrict__ dinv,
                                             float* __restrict__ U, u16* __restrict__ V,
                                             const float* __restrict__ Wl, const float* __restrict__ bconv,
                                             const float* __restrict__ wconv_next, const float* __restrict__ Wo,
                                             float* __restrict__ out, int N, int last){
  __shared__ __align__(16) u16 wb[64*STK];   // (Wl + [I|0]) bf16 [o][c]
  __shared__ __align__(16) u16 an[64*STK];   // concat(x_, g) bf16 [node][c]
  int tid = threadIdx.x;
  for (int i = tid; i < 8192; i += 256){
    int o = i >> 7, c = i & 127;
    wb[o*STK+c] = f2b(Wl[i] + ((c == o) ? 1.f : 0.f));
  }
  int nb0 = blockIdx.x*64;
  for (int i = tid; i < 4096; i += 256){
    int nn = i >> 6, c = i & 63; int n = nb0 + nn;
    u16 xb = 0, gb = 0;
    if (n < N){
      size_t idx = (size_t)n*64 + c;
      xb = xlin[idx];
      float g = dinv[idx]*(b2f(V[idx]) + U[idx]) + bconv[c];
      gb = f2b(g);
      if (!last) U[idx] = 0.f;
    }
    an[nn*STK + c] = xb;
    an[nn*STK + 64 + c] = gb;
  }
  __syncthreads();
  int w = tid >> 6, lane = tid & 63;
  int m16 = lane & 15, quad = lane >> 4;
  int wbase = w*16;
  v8bf af[4];
  #pragma unroll
  for (int ks = 0; ks < 4; ks++) af[ks] = *(const v8bf*)&an[(wbase+m16)*STK + ks*32 + quad*8];
  v4f acc[4];
  #pragma unroll
  for (int ni = 0; ni < 4; ni++) acc[ni] = (v4f){0.f,0.f,0.f,0.f};
  #pragma unroll
  for (int ks = 0; ks < 4; ks++){
    #pragma unroll
    for (int ni = 0; ni < 4; ni++){
      v8bf bf = *(const v8bf*)&wb[(ni*16+m16)*STK + ks*32 + quad*8];
      acc[ni] = __builtin_amdgcn_mfma_f32_16x16x32_bf16(af[ks], bf, acc[ni], 0, 0, 0);
    }
  }
  if (!last){
    #pragma unroll
    for (int ni = 0; ni < 4; ni++){
      int c = ni*16 + m16;
      float wc = wconv_next[c];
      #pragma unroll
      for (int r = 0; r < 4; r++){
        int n = nb0 + wbase + quad*4 + r;
        if (n < N){
          size_t idx = (size_t)n*64 + c;
          V[idx] = f2b(fmaxf(acc[ni][r], 0.f) * wc * dinv[idx]);
        }
      }
    }
  } else {
    float part[4];
    #pragma unroll
    for (int r = 0; r < 4; r++){
      float p = 0.f;
      int rowl = wbase + quad*4 + r;
      #pragma unroll
      for (int ni = 0; ni < 4; ni++){
        int c = ni*16 + m16;
        float xl = b2f(an[rowl*STK + c]);
        float hr = fmaxf(acc[ni][r], 0.f);
        p += xl*Wo[c] + hr*Wo[64 + c];
      }
      part[r] = p;
    }
    #pragma unroll
    for (int off = 1; off < 16; off <<= 1)
      #pragma unroll
      for (int r = 0; r < 4; r++) part[r] += __shfl_xor(part[r], off, 64);
    if (m16 == 0){
      #pragma unroll
      for (int r = 0; r < 4; r++){
        int n = nb0 + wbase + quad*4 + r;
        if (n < N) out[n] = part[r];
      }
    }
  }
}

extern "C" void kernel_launch(void* const* d_in, const int* in_sizes, int n_in,
                              void* d_out, int out_size, void* d_ws, size_t ws_size,
                              hipStream_t stream){
  const float* x     = (const float*)d_in[0];
  const int*   ei    = (const int*)  d_in[1];
  const float* ea    = (const float*)d_in[2];
  const float* W1    = (const float*)d_in[3];
  const float* W2    = (const float*)d_in[4];
  const float* Wi    = (const float*)d_in[5];
  const float* bi    = (const float*)d_in[6];
  const float* wconv = (const float*)d_in[7];
  const float* bconv = (const float*)d_in[8];
  const float* Wl    = (const float*)d_in[9];
  const float* Wo    = (const float*)d_in[10];
  float* out = (float*)d_out;

  int N = in_sizes[0] / 128;
  int E = in_sizes[2] / 8;
  const int* row = ei;
  const int* col = ei + E;

  char* p = (char*)d_ws;
  auto alloc = [&](size_t nbytes){ char* r = p; p += (nbytes + 255) & ~(size_t)255; return r; };

  int*   counts = (int*)  alloc((size_t)N*4);
  int*   start  = (int*)  alloc((size_t)(N+1)*4);
  int*   cursor = (int*)  alloc((size_t)N*4);
  int*   bsum   = (int*)  alloc(4096);
  u32*   rec    = (u32*)  alloc((size_t)E*RW*4);
  float* U      = (float*)alloc((size_t)N*256);
  float* dinv   = (float*)alloc((size_t)N*256);
  u16*   xlin   = (u16*)  alloc((size_t)N*128);
  u16*   V      = (u16*)  alloc((size_t)N*128);

  int gE   = (E + 255) / 256;
  int gA   = (E + EPB - 1) / EPB;
  int nb1  = (N + 1023) / 1024;
  int gN64 = (N + 63) / 64;
  int gNH  = (N*64 + 255) / 256;

  hipMemsetAsync(counts, 0, (size_t)N*4, stream);
  hipMemsetAsync(U, 0, (size_t)N*256, stream);

  hist_k <<<gE, 256, 0, stream>>>(col, counts, E);
  scan1_k<<<nb1, 1024, 0, stream>>>(counts, start, bsum, N);
  scan2_k<<<1, 1024, 0, stream>>>(bsum, nb1, start, N, E);
  scan3_k<<<nb1, 1024, 0, stream>>>(start, bsum, cursor, N);
  scat_k <<<gE, 256, 0, stream>>>(row, col, ea, cursor, rec, E);

  agg_k<0><<<gA, 256, 0, stream>>>(rec, W1, W2, V, U, E);   // degree
  degfin_k<<<gNH, 256, 0, stream>>>(U, dinv, N*64);
  xlin_k  <<<gN64, 256, 0, stream>>>(x, Wi, bi, wconv, dinv, xlin, V, N);

  agg_k<1><<<gA, 256, 0, stream>>>(rec, W1, W2, V, U, E);
  epi_k   <<<gN64, 256, 0, stream>>>(xlin, dinv, U, V, Wl + 0*8192, bconv +   0, wconv +  64, Wo, out, N, 0);
  agg_k<1><<<gA, 256, 0, stream>>>(rec, W1, W2, V, U, E);
  epi_k   <<<gN64, 256, 0, stream>>>(xlin, dinv, U, V, Wl + 1*8192, bconv +  64, wconv + 128, Wo, out, N, 0);
  agg_k<1><<<gA, 256, 0, stream>>>(rec, W1, W2, V, U, E);
  epi_k   <<<gN64, 256, 0, stream>>>(xlin, dinv, U, V, Wl + 2*8192, bconv + 128, wconv      , Wo, out, N, 1);
}